// Round 1
// baseline (2444.446 us; speedup 1.0000x reference)
//
#include <hip/hip_runtime.h>
#include <hip/hip_bf16.h>

// f32 -> bf16 round-to-nearest-even (inputs are finite, no NaN handling needed)
static __device__ __forceinline__ unsigned short f2bf(float f) {
  unsigned int u = __float_as_uint(f);
  u += 0x7fffu + ((u >> 16) & 1u);
  return (unsigned short)(u >> 16);
}

// ---------------------------------------------------------------------------
// Kernel A: per-point MLP (6->32->128->256) fused with segment-max.
// One wave (64 threads) per block, one point per thread.
// h2 (128 per point) staged as bf16 in LDS so layer-3's k loop can runtime-
// index it; w1/w2/w3 are read with wave-uniform indices (-> s_load / SMEM).
// Segment max: batch is sorted, so each wave holds contiguous runs; do a
// segmented suffix-max with masked shfl_down, then only run leaders issue a
// global atomicMax (int-compare trick; buffer pre-zeroed implements clamp@0).
// ---------------------------------------------------------------------------
__global__ __launch_bounds__(64, 2) void mlp_segmax_kernel(
    const float* __restrict__ points, const float* __restrict__ color,
    const int* __restrict__ batch,
    const float* __restrict__ w1, const float* __restrict__ b1,
    const float* __restrict__ w2, const float* __restrict__ b2,
    const float* __restrict__ w3, const float* __restrict__ b3,
    float* __restrict__ xmax, int N)
{
  // stride 132 bf16 (264 B = 66 words, 66%32=2 -> 16 banks, 4-way on b64: ok)
  __shared__ __align__(16) unsigned short h2s[64][132];

  const int lane = threadIdx.x;
  const long long p = (long long)blockIdx.x * 64 + lane;
  const bool active = (p < (long long)N);
  const int pc = active ? (int)p : (N - 1);

  float in6[6];
  in6[0] = points[pc * 3 + 0];
  in6[1] = points[pc * 3 + 1];
  in6[2] = points[pc * 3 + 2];
  in6[3] = color[pc * 3 + 0];
  in6[4] = color[pc * 3 + 1];
  in6[5] = color[pc * 3 + 2];
  // inactive lanes get unique negative segs so they form length-1 runs
  const int seg = active ? batch[pc] : (-2 - lane);

  // ---- layer 1: 6 -> 32, fully unrolled (static register indexing) ----
  float h1[32];
#pragma unroll
  for (int o = 0; o < 32; ++o) {
    float a = b1[o];
#pragma unroll
    for (int i = 0; i < 6; ++i) a = fmaf(in6[i], w1[o * 6 + i], a);
    h1[o] = fmaxf(a, 0.0f);
  }

  // ---- layer 2: 32 -> 128, two outputs per iter, h2 -> LDS as bf16 ----
  for (int o = 0; o < 128; o += 2) {
    float a0 = b2[o], a1 = b2[o + 1];
#pragma unroll
    for (int i = 0; i < 32; ++i) {
      a0 = fmaf(h1[i], w2[o * 32 + i], a0);
      a1 = fmaf(h1[i], w2[(o + 1) * 32 + i], a1);
    }
    a0 = fmaxf(a0, 0.0f);
    a1 = fmaxf(a1, 0.0f);
    unsigned int pk = (unsigned int)f2bf(a0) | ((unsigned int)f2bf(a1) << 16);
    *reinterpret_cast<unsigned int*>(&h2s[lane][o]) = pk;
  }
  // no __syncthreads needed: each lane reads only its own LDS row (same wave)

  // ---- precompute segmented-reduce masks (runs are contiguous) ----
  bool okd[6];
#pragma unroll
  for (int s = 0; s < 6; ++s) {
    const int d = 1 << s;
    const int os = __shfl_down(seg, d);
    okd[s] = ((lane + d) < 64) && (os == seg);
  }
  const bool leader = (lane == 0) || (__shfl_up(seg, 1) != seg);

  // ---- layer 3: 128 -> 256 in groups of 16 channels, fused segment-max ----
  for (int c0 = 0; c0 < 256; c0 += 16) {
    float acc[16];
#pragma unroll
    for (int j = 0; j < 16; ++j) acc[j] = b3[c0 + j];

    for (int k = 0; k < 128; k += 4) {
      const uint2 raw = *reinterpret_cast<const uint2*>(&h2s[lane][k]);
      const float hh0 = __uint_as_float(raw.x << 16);
      const float hh1 = __uint_as_float(raw.x & 0xffff0000u);
      const float hh2 = __uint_as_float(raw.y << 16);
      const float hh3 = __uint_as_float(raw.y & 0xffff0000u);
#pragma unroll
      for (int j = 0; j < 16; ++j) {
        // wave-uniform address -> scalar loads on the SMEM pipe
        const float4 wv = *reinterpret_cast<const float4*>(w3 + (c0 + j) * 128 + k);
        acc[j] = fmaf(hh0, wv.x, acc[j]);
        acc[j] = fmaf(hh1, wv.y, acc[j]);
        acc[j] = fmaf(hh2, wv.z, acc[j]);
        acc[j] = fmaf(hh3, wv.w, acc[j]);
      }
    }

    // segmented suffix-max across the wave, leaders write global atomicMax
#pragma unroll
    for (int j = 0; j < 16; ++j) {
      float v = acc[j];
#pragma unroll
      for (int s = 0; s < 6; ++s) {
        const float ov = __shfl_down(v, 1 << s);
        v = okd[s] ? fmaxf(v, ov) : v;
      }
      if (active && leader && v > 0.0f) {
        // non-negative floats order as ints; init 0 gives the clamp-at-0
        atomicMax(reinterpret_cast<int*>(&xmax[(long long)seg * 256 + c0 + j]),
                  __float_as_int(v));
      }
    }
  }
}

// ---------------------------------------------------------------------------
// Kernel B: FC head  [B,256] -> 128 -> 64 -> 75, + coef scale/shift.
// 16 batch rows per block, activations staged in LDS.
// ---------------------------------------------------------------------------
__global__ __launch_bounds__(256) void head_kernel(
    const float* __restrict__ xmax,
    const float* __restrict__ fw1, const float* __restrict__ fb1,
    const float* __restrict__ fw2, const float* __restrict__ fb2,
    const float* __restrict__ fw3, const float* __restrict__ fb3,
    const float* __restrict__ cmean, const float* __restrict__ cstd,
    float* __restrict__ out, int B)
{
  __shared__ __align__(16) float xm[16][260];
  __shared__ __align__(16) float h1b[16][132];
  __shared__ __align__(16) float h2b[16][68];

  const int t = threadIdx.x;
  const int bbase = blockIdx.x * 16;

  // stage 16 rows of xmax
  for (int i = t; i < 16 * 256; i += 256) {
    const int bi = i >> 8, k = i & 255;
    const int bb = min(bbase + bi, B - 1);
    xm[bi][k] = xmax[(long long)bb * 256 + k];
  }
  __syncthreads();

  // ---- fc1: 256 -> 128 (thread = (row, 8 outputs)) ----
  {
    const int bi = t >> 4, oi = t & 15;
    float acc[8];
#pragma unroll
    for (int u = 0; u < 8; ++u) acc[u] = fb1[oi * 8 + u];
    for (int k = 0; k < 256; k += 4) {
      const float4 xv = *reinterpret_cast<const float4*>(&xm[bi][k]);
#pragma unroll
      for (int u = 0; u < 8; ++u) {
        const float4 wv = *reinterpret_cast<const float4*>(fw1 + (oi * 8 + u) * 256 + k);
        acc[u] = fmaf(xv.x, wv.x, acc[u]);
        acc[u] = fmaf(xv.y, wv.y, acc[u]);
        acc[u] = fmaf(xv.z, wv.z, acc[u]);
        acc[u] = fmaf(xv.w, wv.w, acc[u]);
      }
    }
#pragma unroll
    for (int u = 0; u < 8; ++u) h1b[bi][oi * 8 + u] = fmaxf(acc[u], 0.0f);
  }
  __syncthreads();

  // ---- fc2: 128 -> 64 (thread = (row, 4 outputs)) ----
  {
    const int bi = t >> 4, oi = t & 15;
    float acc[4];
#pragma unroll
    for (int u = 0; u < 4; ++u) acc[u] = fb2[oi * 4 + u];
    for (int k = 0; k < 128; k += 4) {
      const float4 xv = *reinterpret_cast<const float4*>(&h1b[bi][k]);
#pragma unroll
      for (int u = 0; u < 4; ++u) {
        const float4 wv = *reinterpret_cast<const float4*>(fw2 + (oi * 4 + u) * 128 + k);
        acc[u] = fmaf(xv.x, wv.x, acc[u]);
        acc[u] = fmaf(xv.y, wv.y, acc[u]);
        acc[u] = fmaf(xv.z, wv.z, acc[u]);
        acc[u] = fmaf(xv.w, wv.w, acc[u]);
      }
    }
#pragma unroll
    for (int u = 0; u < 4; ++u) h2b[bi][oi * 4 + u] = fmaxf(acc[u], 0.0f);
  }
  __syncthreads();

  // ---- fc3: 64 -> 75, fused coef scale/shift ----
  for (int i = t; i < 16 * 75; i += 256) {
    const int bi = i / 75, o = i - bi * 75;
    float a = fb3[o];
    for (int k = 0; k < 64; k += 4) {
      const float4 xv = *reinterpret_cast<const float4*>(&h2b[bi][k]);
      const float4 wv = *reinterpret_cast<const float4*>(fw3 + o * 64 + k);
      a = fmaf(xv.x, wv.x, a);
      a = fmaf(xv.y, wv.y, a);
      a = fmaf(xv.z, wv.z, a);
      a = fmaf(xv.w, wv.w, a);
    }
    const int b = bbase + bi;
    if (b < B) out[(long long)b * 75 + o] = fmaf(a, cstd[o], cmean[o]);
  }
}

extern "C" void kernel_launch(void* const* d_in, const int* in_sizes, int n_in,
                              void* d_out, int out_size, void* d_ws, size_t ws_size,
                              hipStream_t stream) {
  const float* points = (const float*)d_in[0];
  const float* color  = (const float*)d_in[1];
  const int*   batch  = (const int*)d_in[2];
  const float* w1  = (const float*)d_in[3];
  const float* b1  = (const float*)d_in[4];
  const float* w2  = (const float*)d_in[5];
  const float* b2  = (const float*)d_in[6];
  const float* w3  = (const float*)d_in[7];
  const float* b3  = (const float*)d_in[8];
  const float* fw1 = (const float*)d_in[9];
  const float* fb1 = (const float*)d_in[10];
  const float* fw2 = (const float*)d_in[11];
  const float* fb2 = (const float*)d_in[12];
  const float* fw3 = (const float*)d_in[13];
  const float* fb3 = (const float*)d_in[14];
  const float* cmean = (const float*)d_in[15];
  const float* cstd  = (const float*)d_in[16];
  float* out = (float*)d_out;

  const int N = in_sizes[2];        // batch has N elements
  const int B = out_size / 75;      // K*CC = 75 outputs per batch row

  float* xmax = (float*)d_ws;       // [B][256] f32 = 4 MB
  hipMemsetAsync(xmax, 0, (size_t)B * 256 * sizeof(float), stream);

  const int gridA = (N + 63) / 64;
  mlp_segmax_kernel<<<gridA, 64, 0, stream>>>(points, color, batch,
                                              w1, b1, w2, b2, w3, b3, xmax, N);

  const int gridB = (B + 15) / 16;
  head_kernel<<<gridB, 256, 0, stream>>>(xmax, fw1, fb1, fw2, fb2, fw3, fb3,
                                         cmean, cstd, out, B);
}

// Round 2
// 472.992 us; speedup vs baseline: 5.1681x; 5.1681x over previous
//
#include <hip/hip_runtime.h>
#include <hip/hip_bf16.h>

typedef __attribute__((ext_vector_type(8))) short short8;
typedef __attribute__((ext_vector_type(16))) float f32x16;

union U8 { short8 s; unsigned int u[4]; };

static __device__ __forceinline__ unsigned short f2bf(float f) {
  unsigned int u = __float_as_uint(f);
  u += 0x7fffu + ((u >> 16) & 1u);
  return (unsigned short)(u >> 16);
}
// v_cvt_pk_bf16_f32: low half = bf16(lo), high half = bf16(hi), RNE
static __device__ __forceinline__ unsigned int cvtpk(float lo, float hi) {
  unsigned int r;
  asm("v_cvt_pk_bf16_f32 %0, %1, %2" : "=v"(r) : "v"(lo), "v"(hi));
  return r;
}
static __device__ __forceinline__ f32x16 MFMA(short8 a, short8 b, f32x16 c) {
  return __builtin_amdgcn_mfma_f32_32x32x16_bf16(a, b, c, 0, 0, 0);
}

// ---------------------------------------------------------------------------
// prep: convert weights to bf16 (w1 padded to K=16) into workspace
// ---------------------------------------------------------------------------
__global__ void prep_weights(const float* __restrict__ w1, const float* __restrict__ w2,
                             const float* __restrict__ w3,
                             unsigned short* __restrict__ w1p, unsigned short* __restrict__ w2b,
                             unsigned short* __restrict__ w3b) {
  int i = blockIdx.x * 256 + threadIdx.x;
  if (i < 512) { int c = i >> 4, k = i & 15; w1p[i] = (k < 6) ? f2bf(w1[c * 6 + k]) : (unsigned short)0; }
  if (i < 4096) w2b[i] = f2bf(w2[i]);
  if (i < 32768) w3b[i] = f2bf(w3[i]);
}

// ---------------------------------------------------------------------------
// Fused per-point MLP (6->32->128->256, bf16 MFMA) + segment-max.
// 4 waves/block; each wave owns a contiguous 512-point chunk (8 iters x 64 pts,
// 2x 32-pt subtiles). L1/L2: D = W . X^T (col=point). L3: D = h2 . w3^T
// (col=channel) so segment-max is an in-lane 16-reg max + shfl_xor(32) merge.
// Running per-segment max in regs; atomicMax(int) flush at seg transitions.
// ---------------------------------------------------------------------------
__global__ __launch_bounds__(256, 2) void mlp_segmax_mfma(
    const float* __restrict__ points, const float* __restrict__ color,
    const int* __restrict__ batch,
    const unsigned short* __restrict__ w1p, const unsigned short* __restrict__ w2b,
    const unsigned short* __restrict__ w3b,
    const float* __restrict__ b1, const float* __restrict__ b2, const float* __restrict__ b3,
    float* __restrict__ xmax, int N)
{
  __shared__ __align__(16) char smem[73728];   // 4 waves x (16KB h2 + 2KB h1)
  const int tid  = threadIdx.x;
  const int wv   = tid >> 6;
  const int lane = tid & 63;
  const int g    = lane >> 5;
  const int l31  = lane & 31;
  char* h2base = smem + wv * 16384;
  char* h1base = smem + 65536 + wv * 2048;

  // bias preloads (channels follow the 32x32 C/D reg map: (r&3)+8*(r>>2)+4g)
  float b1v[16];
#pragma unroll
  for (int r = 0; r < 16; ++r) b1v[r] = b1[(r & 3) + 8 * (r >> 2) + 4 * g];
  unsigned int b2pk[32];
#pragma unroll
  for (int t2 = 0; t2 < 4; ++t2)
#pragma unroll
    for (int q = 0; q < 4; ++q)
#pragma unroll
      for (int h = 0; h < 2; ++h) {
        int ch = 32 * t2 + 8 * q + 4 * g + 2 * h;
        b2pk[t2 * 8 + q * 2 + h] = (unsigned)f2bf(b2[ch]) | ((unsigned)f2bf(b2[ch + 1]) << 16);
      }
  float b3v[8];
#pragma unroll
  for (int t = 0; t < 8; ++t) b3v[t] = b3[32 * t + l31];

  const int wid = blockIdx.x * 4 + wv;
  const long long pstart = (long long)wid * 512;
  int cur = -1;
  float rmax[8];
#pragma unroll
  for (int t = 0; t < 8; ++t) rmax[t] = -INFINITY;

  auto flush = [&]() {
#pragma unroll
    for (int t = 0; t < 8; ++t) {
      float v = fmaxf(rmax[t], __shfl_xor(rmax[t], 32));
      if (lane < 32)
        atomicMax((int*)xmax + cur * 256 + 32 * t + lane, __float_as_int(v));
    }
  };

  for (int it = 0; it < 8; ++it) {
    const long long p0 = pstart + (long long)it * 64;
    if (p0 >= N) break;   // N is a multiple of 64 for this problem

    // opaque pointer copies: defeat LICM hoisting weight fragments across iters
    unsigned long long a1p = (unsigned long long)w1p; asm volatile("" : "+s"(a1p));
    unsigned long long a2p = (unsigned long long)w2b; asm volatile("" : "+s"(a2p));
    unsigned long long a3p = (unsigned long long)w3b; asm volatile("" : "+s"(a3p));
    const unsigned short* w1l = (const unsigned short*)a1p;
    const unsigned short* w2l = (const unsigned short*)a2p;
    const unsigned short* w3l = (const unsigned short*)a3p;

    // ---------------- layers 1+2, per 32-point subtile ----------------
#pragma unroll
    for (int s2 = 0; s2 < 2; ++s2) {
      const int p = (int)p0 + 32 * s2 + l31;
      float px = points[p * 3 + 0], py = points[p * 3 + 1], pz = points[p * 3 + 2];
      float cr = color[p * 3 + 0],  cg = color[p * 3 + 1],  cbv = color[p * 3 + 2];
      unsigned int zm = (g == 0) ? 0xffffffffu : 0u;  // g=1 lanes supply the K-pad (zeros)
      U8 bin;
      bin.u[0] = cvtpk(px, py) & zm;
      bin.u[1] = cvtpk(pz, cr) & zm;
      bin.u[2] = cvtpk(cg, cbv) & zm;
      bin.u[3] = 0;
      short8 a1 = *reinterpret_cast<const short8*>(w1l + l31 * 16 + 8 * g);
      f32x16 c1;
#pragma unroll
      for (int r = 0; r < 16; ++r) c1[r] = b1v[r];
      f32x16 d1 = MFMA(a1, bin.s, c1);          // D[ch][pt], col=pt
      // h1 -> LDS (row = point, 64B rows, slot-XOR (row&3))
#pragma unroll
      for (int q = 0; q < 4; ++q) {
        float f0 = fmaxf(d1[q * 4 + 0], 0.f), f1 = fmaxf(d1[q * 4 + 1], 0.f);
        float f2 = fmaxf(d1[q * 4 + 2], 0.f), f3 = fmaxf(d1[q * 4 + 3], 0.f);
        uint2 w; w.x = cvtpk(f0, f1); w.y = cvtpk(f2, f3);
        *reinterpret_cast<uint2*>(h1base + l31 * 64 + ((q ^ (l31 & 3)) << 4) + 8 * g) = w;
      }
      short8 h1f0 = *reinterpret_cast<const short8*>(h1base + l31 * 64 + (((0 + g) ^ (l31 & 3)) << 4));
      short8 h1f1 = *reinterpret_cast<const short8*>(h1base + l31 * 64 + (((2 + g) ^ (l31 & 3)) << 4));
      const int row = 32 * s2 + l31;
#pragma unroll
      for (int t2 = 0; t2 < 4; ++t2) {
        f32x16 c2;
#pragma unroll
        for (int q = 0; q < 4; ++q) {
          unsigned int pka = b2pk[t2 * 8 + q * 2 + 0], pkb = b2pk[t2 * 8 + q * 2 + 1];
          c2[q * 4 + 0] = __uint_as_float(pka << 16);
          c2[q * 4 + 1] = __uint_as_float(pka & 0xffff0000u);
          c2[q * 4 + 2] = __uint_as_float(pkb << 16);
          c2[q * 4 + 3] = __uint_as_float(pkb & 0xffff0000u);
        }
        short8 a20 = *reinterpret_cast<const short8*>(w2l + (l31 + 32 * t2) * 32 + 8 * g);
        short8 a21 = *reinterpret_cast<const short8*>(w2l + (l31 + 32 * t2) * 32 + 16 + 8 * g);
        f32x16 d2 = MFMA(a20, h1f0, c2);
        d2 = MFMA(a21, h1f1, d2);                // D[ch][pt], col=pt
        // relu + bf16 pack -> h2 LDS (row = point, 256B rows, slot-XOR (row&15))
#pragma unroll
        for (int q = 0; q < 4; ++q) {
          float f0 = fmaxf(d2[q * 4 + 0], 0.f), f1 = fmaxf(d2[q * 4 + 1], 0.f);
          float f2 = fmaxf(d2[q * 4 + 2], 0.f), f3 = fmaxf(d2[q * 4 + 3], 0.f);
          uint2 w; w.x = cvtpk(f0, f1); w.y = cvtpk(f2, f3);
          int slot = q + 4 * t2;
          *reinterpret_cast<uint2*>(h2base + row * 256 + ((slot ^ (row & 15)) << 4) + 8 * g) = w;
        }
      }
    }

    // ---------------- A3 fragments (both subtiles) ----------------
    short8 a3[2][8];
#pragma unroll
    for (int s2 = 0; s2 < 2; ++s2) {
      const int row = 32 * s2 + l31;
#pragma unroll
      for (int k0 = 0; k0 < 8; ++k0)
        a3[s2][k0] = *reinterpret_cast<const short8*>(
            h2base + row * 256 + (((2 * k0 + g) ^ (row & 15)) << 4));
    }

    // ---------------- segment bookkeeping ----------------
    const int segA = __builtin_amdgcn_readfirstlane(batch[p0]);
    const int segD = __builtin_amdgcn_readfirstlane(batch[p0 + 63]);
    const bool caseU = (segA == segD);
    unsigned int bitsA0 = 0, bitsD0 = 0, bitsA1 = 0, bitsD1 = 0;
    if (caseU) {
      if (segA != cur) {
        if (cur >= 0) flush();
        cur = segA;
#pragma unroll
        for (int t = 0; t < 8; ++t) rmax[t] = -INFINITY;
      }
    } else {
      if (cur >= 0 && cur != segA) flush();
      if (cur != segA) {
#pragma unroll
        for (int t = 0; t < 8; ++t) rmax[t] = -INFINITY;
        cur = segA;
      }
#pragma unroll
      for (int s2 = 0; s2 < 2; ++s2) {
        unsigned int bA = 0, bD = 0;
#pragma unroll
        for (int r = 0; r < 16; ++r) {
          int pr = (int)p0 + 32 * s2 + (r & 3) + 8 * (r >> 2) + 4 * g;
          int bs = batch[pr];
          bA |= (bs == segA) ? (1u << r) : 0u;
          bD |= (bs == segD) ? (1u << r) : 0u;
        }
        if (s2 == 0) { bitsA0 = bA; bitsD0 = bD; } else { bitsA1 = bA; bitsD1 = bD; }
      }
    }

    float m_a[8], m_d[8];
    // ---------------- layer 3: D = h2 . w3^T, col=channel ----------------
#pragma unroll
    for (int t = 0; t < 8; ++t) {
      f32x16 acc0, acc1;
#pragma unroll
      for (int r = 0; r < 16; ++r) { acc0[r] = b3v[t]; acc1[r] = b3v[t]; }
#pragma unroll
      for (int hh = 0; hh < 2; ++hh) {
        short8 bf[4];
#pragma unroll
        for (int k = 0; k < 4; ++k)
          bf[k] = *reinterpret_cast<const short8*>(
              w3l + (l31 + 32 * t) * 128 + (4 * hh + k) * 16 + 8 * g);
#pragma unroll
        for (int k = 0; k < 4; ++k) {
          acc0 = MFMA(a3[0][4 * hh + k], bf[k], acc0);
          acc1 = MFMA(a3[1][4 * hh + k], bf[k], acc1);
        }
      }
      if (caseU) {
        float m = acc0[0];
#pragma unroll
        for (int r = 1; r < 16; ++r) m = fmaxf(m, acc0[r]);
#pragma unroll
        for (int r = 0; r < 16; ++r) m = fmaxf(m, acc1[r]);
        rmax[t] = fmaxf(rmax[t], m);
      } else {
        float ma = -INFINITY, md = -INFINITY;
#pragma unroll
        for (int r = 0; r < 16; ++r) {
          float v0 = acc0[r], v1 = acc1[r];
          ma = fmaxf(ma, ((bitsA0 >> r) & 1) ? v0 : -INFINITY);
          md = fmaxf(md, ((bitsD0 >> r) & 1) ? v0 : -INFINITY);
          ma = fmaxf(ma, ((bitsA1 >> r) & 1) ? v1 : -INFINITY);
          md = fmaxf(md, ((bitsD1 >> r) & 1) ? v1 : -INFINITY);
        }
        unsigned int rest0 = (~(bitsA0 | bitsD0)) & 0xffffu;
        if (rest0) {
#pragma unroll
          for (int r = 0; r < 16; ++r) if ((rest0 >> r) & 1) {
            int pr = (int)p0 + (r & 3) + 8 * (r >> 2) + 4 * g;
            atomicMax((int*)xmax + batch[pr] * 256 + 32 * t + l31, __float_as_int(acc0[r]));
          }
        }
        unsigned int rest1 = (~(bitsA1 | bitsD1)) & 0xffffu;
        if (rest1) {
#pragma unroll
          for (int r = 0; r < 16; ++r) if ((rest1 >> r) & 1) {
            int pr = (int)p0 + 32 + (r & 3) + 8 * (r >> 2) + 4 * g;
            atomicMax((int*)xmax + batch[pr] * 256 + 32 * t + l31, __float_as_int(acc1[r]));
          }
        }
        m_a[t] = ma; m_d[t] = md;
      }
    }
    if (!caseU) {
#pragma unroll
      for (int t = 0; t < 8; ++t) rmax[t] = fmaxf(rmax[t], m_a[t]);
      flush();                       // closes segA
      cur = segD;
#pragma unroll
      for (int t = 0; t < 8; ++t) rmax[t] = m_d[t];
    }
  }
  if (cur >= 0) flush();
}

// ---------------------------------------------------------------------------
// FC head  [B,256] -> 128 -> 64 -> 75, + coef scale/shift (unchanged, passed R1)
// ---------------------------------------------------------------------------
__global__ __launch_bounds__(256) void head_kernel(
    const float* __restrict__ xmax,
    const float* __restrict__ fw1, const float* __restrict__ fb1,
    const float* __restrict__ fw2, const float* __restrict__ fb2,
    const float* __restrict__ fw3, const float* __restrict__ fb3,
    const float* __restrict__ cmean, const float* __restrict__ cstd,
    float* __restrict__ out, int B)
{
  __shared__ __align__(16) float xm[16][260];
  __shared__ __align__(16) float h1b[16][132];
  __shared__ __align__(16) float h2b[16][68];

  const int t = threadIdx.x;
  const int bbase = blockIdx.x * 16;

  for (int i = t; i < 16 * 256; i += 256) {
    const int bi = i >> 8, k = i & 255;
    const int bb = min(bbase + bi, B - 1);
    xm[bi][k] = xmax[(long long)bb * 256 + k];
  }
  __syncthreads();

  {
    const int bi = t >> 4, oi = t & 15;
    float acc[8];
#pragma unroll
    for (int u = 0; u < 8; ++u) acc[u] = fb1[oi * 8 + u];
    for (int k = 0; k < 256; k += 4) {
      const float4 xv = *reinterpret_cast<const float4*>(&xm[bi][k]);
#pragma unroll
      for (int u = 0; u < 8; ++u) {
        const float4 wv = *reinterpret_cast<const float4*>(fw1 + (oi * 8 + u) * 256 + k);
        acc[u] = fmaf(xv.x, wv.x, acc[u]);
        acc[u] = fmaf(xv.y, wv.y, acc[u]);
        acc[u] = fmaf(xv.z, wv.z, acc[u]);
        acc[u] = fmaf(xv.w, wv.w, acc[u]);
      }
    }
#pragma unroll
    for (int u = 0; u < 8; ++u) h1b[bi][oi * 8 + u] = fmaxf(acc[u], 0.0f);
  }
  __syncthreads();

  {
    const int bi = t >> 4, oi = t & 15;
    float acc[4];
#pragma unroll
    for (int u = 0; u < 4; ++u) acc[u] = fb2[oi * 4 + u];
    for (int k = 0; k < 128; k += 4) {
      const float4 xv = *reinterpret_cast<const float4*>(&h1b[bi][k]);
#pragma unroll
      for (int u = 0; u < 4; ++u) {
        const float4 wv = *reinterpret_cast<const float4*>(fw2 + (oi * 4 + u) * 128 + k);
        acc[u] = fmaf(xv.x, wv.x, acc[u]);
        acc[u] = fmaf(xv.y, wv.y, acc[u]);
        acc[u] = fmaf(xv.z, wv.z, acc[u]);
        acc[u] = fmaf(xv.w, wv.w, acc[u]);
      }
    }
#pragma unroll
    for (int u = 0; u < 4; ++u) h2b[bi][oi * 4 + u] = fmaxf(acc[u], 0.0f);
  }
  __syncthreads();

  for (int i = t; i < 16 * 75; i += 256) {
    const int bi = i / 75, o = i - bi * 75;
    float a = fb3[o];
    for (int k = 0; k < 64; k += 4) {
      const float4 xv = *reinterpret_cast<const float4*>(&h2b[bi][k]);
      const float4 wv = *reinterpret_cast<const float4*>(fw3 + o * 64 + k);
      a = fmaf(xv.x, wv.x, a);
      a = fmaf(xv.y, wv.y, a);
      a = fmaf(xv.z, wv.z, a);
      a = fmaf(xv.w, wv.w, a);
    }
    const int b = bbase + bi;
    if (b < B) out[(long long)b * 75 + o] = fmaf(a, cstd[o], cmean[o]);
  }
}

extern "C" void kernel_launch(void* const* d_in, const int* in_sizes, int n_in,
                              void* d_out, int out_size, void* d_ws, size_t ws_size,
                              hipStream_t stream) {
  const float* points = (const float*)d_in[0];
  const float* color  = (const float*)d_in[1];
  const int*   batch  = (const int*)d_in[2];
  const float* w1  = (const float*)d_in[3];
  const float* b1  = (const float*)d_in[4];
  const float* w2  = (const float*)d_in[5];
  const float* b2  = (const float*)d_in[6];
  const float* w3  = (const float*)d_in[7];
  const float* b3  = (const float*)d_in[8];
  const float* fw1 = (const float*)d_in[9];
  const float* fb1 = (const float*)d_in[10];
  const float* fw2 = (const float*)d_in[11];
  const float* fb2 = (const float*)d_in[12];
  const float* fw3 = (const float*)d_in[13];
  const float* fb3 = (const float*)d_in[14];
  const float* cmean = (const float*)d_in[15];
  const float* cstd  = (const float*)d_in[16];
  float* out = (float*)d_out;

  const int N = in_sizes[2];
  const int B = out_size / 75;

  float* xmax = (float*)d_ws;                                  // [B][256] f32 = 4MB
  unsigned short* w1p = (unsigned short*)((char*)d_ws + 4194304);   // 32x16 bf16
  unsigned short* w2b = (unsigned short*)((char*)d_ws + 4195328);   // 128x32 bf16
  unsigned short* w3b = (unsigned short*)((char*)d_ws + 4203520);   // 256x128 bf16

  hipMemsetAsync(xmax, 0, (size_t)B * 256 * sizeof(float), stream);
  prep_weights<<<128, 256, 0, stream>>>(w1, w2, w3, w1p, w2b, w3b);

  const int nWaves = 2048;                 // 512 pts/wave covers N=1M
  mlp_segmax_mfma<<<nWaves / 4, 256, 0, stream>>>(points, color, batch,
                                                  w1p, w2b, w3b, b1, b2, b3, xmax, N);

  head_kernel<<<(B + 15) / 16, 256, 0, stream>>>(xmax, fw1, fb1, fw2, fb2, fw3, fb3,
                                                 cmean, cstd, out, B);
}